// Round 1
// baseline (392.295 us; speedup 1.0000x reference)
//
#include <hip/hip_runtime.h>

// Problem: B=8192, NOBJ=1024; inputs [B,NOBJ,2,3] f32; only row 1 (euler) used.
// loss = sum over pairs of acos(clip(0.5*(trace(Rs*Rt^T)-1))) / B
#define NPAIRS (8192u * 1024u)   // 8,388,608
#define BLOCK  256
#define GRID   2048
#define EPSF   1e-6f

// trace(R(e0) * R(e1)^T) = elementwise dot of the two rotation matrices.
// R = RZ(yaw) @ RY(pitch) @ RX(roll):
//   [ cy*cp   cy*sp*sr - sy*cr   cy*sp*cr + sy*sr ]
//   [ sy*cp   sy*sp*sr + cy*cr   sy*sp*cr - cy*sr ]
//   [ -sp     cp*sr              cp*cr            ]
__device__ __forceinline__ float pair_loss(float r0, float p0, float y0,
                                           float r1, float p1, float y1) {
    float sr0 = __sinf(r0), cr0 = __cosf(r0);
    float sp0 = __sinf(p0), cp0 = __cosf(p0);
    float sy0 = __sinf(y0), cy0 = __cosf(y0);
    float sr1 = __sinf(r1), cr1 = __cosf(r1);
    float sp1 = __sinf(p1), cp1 = __cosf(p1);
    float sy1 = __sinf(y1), cy1 = __cosf(y1);

    float cysp0 = cy0 * sp0, sysp0 = sy0 * sp0;
    float cysp1 = cy1 * sp1, sysp1 = sy1 * sp1;

    float a00 = cy0 * cp0,               b00 = cy1 * cp1;
    float a01 = cysp0 * sr0 - sy0 * cr0, b01 = cysp1 * sr1 - sy1 * cr1;
    float a02 = cysp0 * cr0 + sy0 * sr0, b02 = cysp1 * cr1 + sy1 * sr1;
    float a10 = sy0 * cp0,               b10 = sy1 * cp1;
    float a11 = sysp0 * sr0 + cy0 * cr0, b11 = sysp1 * sr1 + cy1 * cr1;
    float a12 = sysp0 * cr0 - cy0 * sr0, b12 = sysp1 * cr1 - cy1 * sr1;
    float a20 = -sp0,                    b20 = -sp1;
    float a21 = cp0 * sr0,               b21 = cp1 * sr1;
    float a22 = cp0 * cr0,               b22 = cp1 * cr1;

    float tr = a00 * b00;
    tr = fmaf(a01, b01, tr);
    tr = fmaf(a02, b02, tr);
    tr = fmaf(a10, b10, tr);
    tr = fmaf(a11, b11, tr);
    tr = fmaf(a12, b12, tr);
    tr = fmaf(a20, b20, tr);
    tr = fmaf(a21, b21, tr);
    tr = fmaf(a22, b22, tr);

    float theta = 0.5f * (tr - 1.0f);
    theta = fminf(fmaxf(theta, -1.0f + EPSF), 1.0f - EPSF);
    return acosf(theta);
}

// Each iteration handles 2 consecutive pairs = 12 floats = 3 float4 per tensor.
// 48-byte chunk base is 16B-aligned -> perfectly vectorized/coalesced loads.
// Layout per chunk: [t0 t1 t2 | e0 e1 e2 | T0 T1 T2 | E0 E1 E2]
//   pair A euler = f4_0.w, f4_1.x, f4_1.y ; pair B euler = f4_2.y, f4_2.z, f4_2.w
__global__ __launch_bounds__(BLOCK) void rot_loss_partial(
    const float4* __restrict__ outp, const float4* __restrict__ targ,
    float* __restrict__ partial) {
    const unsigned tid = blockIdx.x * BLOCK + threadIdx.x;
    const unsigned nthreads = GRID * BLOCK;
    const unsigned nchunks = NPAIRS / 2;  // 4,194,304

    float acc = 0.0f;
    for (unsigned i = tid; i < nchunks; i += nthreads) {
        const unsigned base = 3u * i;
        float4 o0 = outp[base + 0];
        float4 o1 = outp[base + 1];
        float4 o2 = outp[base + 2];
        float4 t0 = targ[base + 0];
        float4 t1 = targ[base + 1];
        float4 t2 = targ[base + 2];
        acc += pair_loss(o0.w, o1.x, o1.y, t0.w, t1.x, t1.y);
        acc += pair_loss(o2.y, o2.z, o2.w, t2.y, t2.z, t2.w);
    }

    // wave-64 shuffle reduce
    #pragma unroll
    for (int off = 32; off > 0; off >>= 1) acc += __shfl_down(acc, off);

    __shared__ float ws[BLOCK / 64];
    const int lane = threadIdx.x & 63;
    const int wave = threadIdx.x >> 6;
    if (lane == 0) ws[wave] = acc;
    __syncthreads();
    if (threadIdx.x == 0) {
        float s = 0.0f;
        #pragma unroll
        for (int w = 0; w < BLOCK / 64; ++w) s += ws[w];
        partial[blockIdx.x] = s;  // written unconditionally (d_ws is poisoned)
    }
}

__global__ __launch_bounds__(BLOCK) void rot_loss_final(
    const float* __restrict__ partial, float* __restrict__ out) {
    double acc = 0.0;
    for (int i = threadIdx.x; i < GRID; i += BLOCK) acc += (double)partial[i];
    #pragma unroll
    for (int off = 32; off > 0; off >>= 1) acc += __shfl_down(acc, off);
    __shared__ double ws[BLOCK / 64];
    const int lane = threadIdx.x & 63;
    const int wave = threadIdx.x >> 6;
    if (lane == 0) ws[wave] = acc;
    __syncthreads();
    if (threadIdx.x == 0) {
        double s = 0.0;
        #pragma unroll
        for (int w = 0; w < BLOCK / 64; ++w) s += ws[w];
        out[0] = (float)(s / 8192.0);
    }
}

extern "C" void kernel_launch(void* const* d_in, const int* in_sizes, int n_in,
                              void* d_out, int out_size, void* d_ws, size_t ws_size,
                              hipStream_t stream) {
    const float4* outp = (const float4*)d_in[0];
    const float4* targ = (const float4*)d_in[1];
    float* partial = (float*)d_ws;  // GRID floats = 8 KiB
    float* out = (float*)d_out;

    rot_loss_partial<<<GRID, BLOCK, 0, stream>>>(outp, targ, partial);
    rot_loss_final<<<1, BLOCK, 0, stream>>>(partial, out);
}

// Round 2
// 389.903 us; speedup vs baseline: 1.0061x; 1.0061x over previous
//
#include <hip/hip_runtime.h>

// Problem: B=8192, NOBJ=1024; inputs [B,NOBJ,2,3] f32; only row 1 (euler) used.
// loss = sum over pairs of acos(clip(0.5*(trace(Rs*Rt^T)-1))) / B
#define NPAIRS (8192u * 1024u)   // 8,388,608
#define BLOCK  256
#define GRID   2048
#define EPSF   1e-6f

// trace(R(e0) R(e1)^T) reduced to angle differences (verified vs matrix form):
//   trace = cp0*cp1*(cos(dr) + cos(dy)) + sp0*sp1
//         + (1 + sp0*sp1)*cos(dr)*cos(dy) + (sp0+sp1)*sin(dr)*sin(dy)
// with dr = r1-r0, dy = y1-y0 (same orientation for both — the sdr*sdy
// product needs consistent signs).
__device__ __forceinline__ float pair_loss(float r0, float p0, float y0,
                                           float r1, float p1, float y1) {
    float sp0 = __sinf(p0), cp0 = __cosf(p0);
    float sp1 = __sinf(p1), cp1 = __cosf(p1);
    float dr = r1 - r0, dy = y1 - y0;
    float sdr = __sinf(dr), cdr = __cosf(dr);
    float sdy = __sinf(dy), cdy = __cosf(dy);

    float m2 = sp0 * sp1;
    float cc = cdr * cdy;
    float tr = cp0 * cp1 * (cdr + cdy);
    tr += m2;
    tr += fmaf(m2, cc, cc);                    // (1 + sp0*sp1)*cc
    tr = fmaf(sp0 + sp1, sdr * sdy, tr);

    float theta = fmaf(0.5f, tr, -0.5f);
    theta = fminf(fmaxf(theta, -1.0f + EPSF), 1.0f - EPSF);
    return acosf(theta);
}

// Each chunk = 2 consecutive pairs = 12 floats = 3 float4 per tensor.
// Chunk layout: [t0 t1 t2 | e0 e1 e2 | T0 T1 T2 | E0 E1 E2]
//   pair A euler = f4_0.w, f4_1.x, f4_1.y ; pair B euler = f4_2.y, f4_2.z, f4_2.w
// Manual 1-deep software pipeline: issue chunk i+1's loads BEFORE computing
// chunk i, so the ~600-900cy miss latency hides under compute of the
// resident waves instead of being exposed at a vmcnt(0) every iteration.
__global__ __launch_bounds__(BLOCK) void rot_loss_partial(
    const float4* __restrict__ outp, const float4* __restrict__ targ,
    float* __restrict__ partial) {
    const unsigned tid = blockIdx.x * BLOCK + threadIdx.x;
    const unsigned nthreads = GRID * BLOCK;
    const unsigned nchunks = NPAIRS / 2;  // 4,194,304 ; exactly 8 per thread

    float acc = 0.0f;
    unsigned i = tid;
    unsigned b = 3u * i;
    float4 o0 = outp[b], o1 = outp[b + 1], o2 = outp[b + 2];
    float4 t0 = targ[b], t1 = targ[b + 1], t2 = targ[b + 2];

    #pragma unroll 1
    for (;;) {
        const unsigned inext = i + nthreads;
        const bool more = inext < nchunks;   // uniform across all threads
        float4 no0, no1, no2, nt0, nt1, nt2;
        if (more) {
            const unsigned nb = 3u * inext;
            no0 = outp[nb]; no1 = outp[nb + 1]; no2 = outp[nb + 2];
            nt0 = targ[nb]; nt1 = targ[nb + 1]; nt2 = targ[nb + 2];
        }
        acc += pair_loss(o0.w, o1.x, o1.y, t0.w, t1.x, t1.y);
        acc += pair_loss(o2.y, o2.z, o2.w, t2.y, t2.z, t2.w);
        if (!more) break;
        o0 = no0; o1 = no1; o2 = no2;
        t0 = nt0; t1 = nt1; t2 = nt2;
        i = inext;
    }

    // wave-64 shuffle reduce
    #pragma unroll
    for (int off = 32; off > 0; off >>= 1) acc += __shfl_down(acc, off);

    __shared__ float ws[BLOCK / 64];
    const int lane = threadIdx.x & 63;
    const int wave = threadIdx.x >> 6;
    if (lane == 0) ws[wave] = acc;
    __syncthreads();
    if (threadIdx.x == 0) {
        float s = 0.0f;
        #pragma unroll
        for (int w = 0; w < BLOCK / 64; ++w) s += ws[w];
        partial[blockIdx.x] = s;  // written unconditionally (d_ws is poisoned)
    }
}

__global__ __launch_bounds__(BLOCK) void rot_loss_final(
    const float* __restrict__ partial, float* __restrict__ out) {
    double acc = 0.0;
    for (int i = threadIdx.x; i < GRID; i += BLOCK) acc += (double)partial[i];
    #pragma unroll
    for (int off = 32; off > 0; off >>= 1) acc += __shfl_down(acc, off);
    __shared__ double ws[BLOCK / 64];
    const int lane = threadIdx.x & 63;
    const int wave = threadIdx.x >> 6;
    if (lane == 0) ws[wave] = acc;
    __syncthreads();
    if (threadIdx.x == 0) {
        double s = 0.0;
        #pragma unroll
        for (int w = 0; w < BLOCK / 64; ++w) s += ws[w];
        out[0] = (float)(s / 8192.0);
    }
}

extern "C" void kernel_launch(void* const* d_in, const int* in_sizes, int n_in,
                              void* d_out, int out_size, void* d_ws, size_t ws_size,
                              hipStream_t stream) {
    const float4* outp = (const float4*)d_in[0];
    const float4* targ = (const float4*)d_in[1];
    float* partial = (float*)d_ws;  // GRID floats = 8 KiB
    float* out = (float*)d_out;

    rot_loss_partial<<<GRID, BLOCK, 0, stream>>>(outp, targ, partial);
    rot_loss_final<<<1, BLOCK, 0, stream>>>(partial, out);
}